// Round 1
// baseline (9.273 us; speedup 1.0000x reference)
//
#include <hip/hip_runtime.h>
#include <hip/hip_bf16.h>

// sum(fft2(x)) over all elements == H*W * sum_b x[b,0,0]  (imag == 0)
// Proof: sum_{k} e^{-2pi i k m / H} = H * [m==0], same for l/n.
// x: [32, 2048, 2048] f32 -> complex64 scalar = 2 floats {re, im}.

__global__ void TorchModel_77223511982255_kernel(const float* __restrict__ x,
                                                 float* __restrict__ out,
                                                 int out_size) {
    const int lane = threadIdx.x;           // one wave of 64 lanes
    float v = 0.0f;
    if (lane < 32) {
        // batch stride = 2048*2048 elements = 4 MiB
        v = x[(size_t)lane * 2048u * 2048u];
    }
    // full-wave butterfly reduction (lanes >= 32 contribute 0)
    #pragma unroll
    for (int off = 32; off > 0; off >>= 1) {
        v += __shfl_down(v, off, 64);
    }
    if (lane == 0) {
        out[0] = v * 4194304.0f;            // * (2048*2048)
        if (out_size > 1) out[1] = 0.0f;    // imaginary part
    }
}

extern "C" void kernel_launch(void* const* d_in, const int* in_sizes, int n_in,
                              void* d_out, int out_size, void* d_ws, size_t ws_size,
                              hipStream_t stream) {
    (void)in_sizes; (void)n_in; (void)d_ws; (void)ws_size;
    const float* x = (const float*)d_in[0];
    float* out = (float*)d_out;
    TorchModel_77223511982255_kernel<<<1, 64, 0, stream>>>(x, out, out_size);
}